// Round 3
// baseline (232.665 us; speedup 1.0000x reference)
//
#include <hip/hip_runtime.h>
#include <hip/hip_bf16.h>
#include <math.h>

// Problem constants (from reference setup_inputs)
#define BATCH 8
#define SEQ   1536
#define DIM   1024
#define SEQ2  (2*SEQ)          // 3072
#define TEMP_INV 20.0f         // 1 / 0.05
// feats stored as fp8 e4m3 pre-scaled by 8 => sim accumulator carries 64x
#define EXP_SCALE (TEMP_INV / 64.0f)   // 0.3125

// GEMM tiling: 256x256 tile, 8 waves (2x4), 8-phase counted-vmcnt schedule
#define BM 256
#define BN 256
#define BK 128                          // fp8 bytes per row per K-tile
#define KTILES (DIM/BK)                 // 8
#define GITERS (KTILES/2)               // 4 (2 K-tiles per iter; last is peeled)
#define TILES  (SEQ2 / BM)              // 12
#define NPAIRS (TILES * (TILES+1) / 2)  // 78 upper-triangular tile pairs

typedef int   i32x4 __attribute__((ext_vector_type(4)));
typedef int   i32x8 __attribute__((ext_vector_type(8)));
typedef float f32x4 __attribute__((ext_vector_type(4)));

#define GLOBAL_AS __attribute__((address_space(1)))
#define LDS_AS    __attribute__((address_space(3)))

__device__ inline void async_ld16(const void* g, void* lds_uniform) {
    // gfx950: direct global->LDS, 16B/lane; LDS dest = wave-uniform base + lane*16
    __builtin_amdgcn_global_load_lds((const GLOBAL_AS void*)g, (LDS_AS void*)lds_uniform, 16, 0, 0);
}

__device__ inline float wave_red64(float v) {
    #pragma unroll
    for (int m = 32; m > 0; m >>= 1) v += __shfl_xor(v, m, 64);
    return v;
}

// ---------------------------------------------------------------------------
// Kernel 1: L2-normalize both views -> fp8 e4m3 feats (x8 pre-scale)
// ---------------------------------------------------------------------------
__global__ __launch_bounds__(256) void normalize_kernel(
        const float* __restrict__ h1, const float* __restrict__ h2,
        unsigned char* __restrict__ feats, float* __restrict__ pos_cos,
        float* __restrict__ Ng, float* __restrict__ out) {
    int w = threadIdx.x >> 6, lane = threadIdx.x & 63;
    int tok = blockIdx.x * 4 + w;                 // 0 .. B*S-1
    int b = tok / SEQ, s = tok - b * SEQ;

    const float4* a4 = (const float4*)(h1 + (size_t)tok * DIM);
    const float4* b4 = (const float4*)(h2 + (size_t)tok * DIM);
    float4 av[4], bv[4];
    #pragma unroll
    for (int it = 0; it < 4; it++) { av[it] = a4[lane + 64*it]; bv[it] = b4[lane + 64*it]; }

    float ss1 = 0.f, ss2 = 0.f, sd = 0.f;
    #pragma unroll
    for (int it = 0; it < 4; it++) {
        ss1 += av[it].x*av[it].x + av[it].y*av[it].y + av[it].z*av[it].z + av[it].w*av[it].w;
        ss2 += bv[it].x*bv[it].x + bv[it].y*bv[it].y + bv[it].z*bv[it].z + bv[it].w*bv[it].w;
        sd  += av[it].x*bv[it].x + av[it].y*bv[it].y + av[it].z*bv[it].z + av[it].w*bv[it].w;
    }
    ss1 = wave_red64(ss1); ss2 = wave_red64(ss2); sd = wave_red64(sd);

    float sc1 = 1.0f / fmaxf(sqrtf(ss1), 1e-12f);
    float sc2 = 1.0f / fmaxf(sqrtf(ss2), 1e-12f);
    float s18 = sc1 * 8.0f, s28 = sc2 * 8.0f;   // x8: keep fp8 values normal

    unsigned int* f1row = (unsigned int*)(feats + ((size_t)b * SEQ2 + s) * DIM);
    unsigned int* f2row = (unsigned int*)(feats + ((size_t)b * SEQ2 + SEQ + s) * DIM);
    #pragma unroll
    for (int it = 0; it < 4; it++) {
        int p1 = __builtin_amdgcn_cvt_pk_fp8_f32(av[it].x * s18, av[it].y * s18, 0, 0);
        p1     = __builtin_amdgcn_cvt_pk_fp8_f32(av[it].z * s18, av[it].w * s18, p1, 1);
        int p2 = __builtin_amdgcn_cvt_pk_fp8_f32(bv[it].x * s28, bv[it].y * s28, 0, 0);
        p2     = __builtin_amdgcn_cvt_pk_fp8_f32(bv[it].z * s28, bv[it].w * s28, p2, 1);
        f1row[lane + 64*it] = (unsigned int)p1;
        f2row[lane + 64*it] = (unsigned int)p2;
    }
    if (lane == 0) {
        pos_cos[tok] = sd * sc1 * sc2;
        Ng[2*tok] = 0.0f;
        Ng[2*tok + 1] = 0.0f;
        if (tok == 0) out[0] = 0.0f;   // loss blocks accumulate into out
    }
}

// ---------------------------------------------------------------------------
// Kernel 2: symmetric fused sim-GEMM + exp + neg-mask, MX-fp8 K=128.
// 256x256 tile, 8 waves (2x4 -> 128x64 per wave), 8-phase counted-vmcnt
// schedule (sync structure identical to R1/R2, verified race-free).
// R3 change (register pressure): the Q10 phases RE-READ the p-fragments
// from LDS instead of keeping them live across 4 phases.  Peak concurrent
// fragment-live drops 64 -> 48 regs and no frag value crosses >2 barriers,
// fitting the 256-reg/wave cap (acc=128 + frags<=48 + addressing) without
// scratch spill (R2: 27 MB scratch writes on the critical path).
// Safety of re-read: the active dbuf's B-half is never a DMA target during
// its own K-tile phases (stages write the OTHER dbuf's B / same dbuf's A),
// and it fully landed at this K-tile's entry vmcnt+barrier.
// vmcnt accounting unchanged: 10 outstanding at each VM2, oldest 8 = the
// K-tile about to be consumed.
// ---------------------------------------------------------------------------
__global__ __launch_bounds__(512, 2) void gemm_ng_kernel(
        const unsigned char* __restrict__ feats, const int* __restrict__ mask,
        float* __restrict__ Ng) {
    int bid = blockIdx.x;
    int b = bid & 7;                 // XCD-local batch; 624 % 8 == 0
    int p = bid >> 3;                // 0..77 triangular pair index
    int ti = 0;
    while (p >= TILES - ti) { p -= TILES - ti; ti++; }
    int tj = ti + p;
    int ibase = ti * BM, jbase = tj * BN;
    bool isdiag = (ti == tj);

    const unsigned char* fb = feats + (size_t)b * SEQ2 * DIM;

    __shared__ __align__(16) unsigned char As[2][2][128][BK];  // 64 KB [dbuf][half]
    __shared__ __align__(16) unsigned char Bs[2][2][128][BK];  // 64 KB
    __shared__ float mrow_s[BM];
    __shared__ float mcol_s[BN];

    int t = threadIdx.x;
    int lane = t & 63, w = t >> 6;          // 8 waves
    int wrow = w >> 2, wcol = w & 3;        // 2x4 -> 128x64 per wave
    int colq = lane & 15, quad = lane >> 4;

    // Staging source: lane covers LDS bytes (w*2048 + {0,1024} + lane*16) of a
    // 16KB half-tile -> row = w*16 + {0,8} + (lane>>3), slot = lane&7.
    // Swizzle: chunk for slot s at row r is s ^ (r&7); here r&7 == lane>>3.
    int sr8 = lane >> 3;
    int sc  = (lane & 7) ^ sr8;
    const unsigned char* aSrc = fb + (size_t)(ibase + w*16 + sr8) * DIM + sc*16;
    const unsigned char* bSrc = fb + (size_t)(jbase + w*16 + sr8) * DIM + sc*16;

    auto stA = [&](int kt, int d, int h) {
        char* lb = (char*)&As[d][h][0][0] + w * 2048;
        const unsigned char* g = aSrc + (size_t)h * (128*DIM) + (size_t)kt * BK;
        async_ld16(g,           lb);
        async_ld16(g + 8*DIM,   lb + 1024);
    };
    auto stB = [&](int kt, int d, int h) {
        char* lb = (char*)&Bs[d][h][0][0] + w * 2048;
        const unsigned char* g = bSrc + (size_t)h * (128*DIM) + (size_t)kt * BK;
        async_ld16(g,           lb);
        async_ld16(g + 8*DIM,   lb + 1024);
    };

    // Prologue: K-tile 0 fully + A(1) half0 (the virtual iter -1 ph8 slot)
    stA(0,0,0); stA(0,0,1); stB(0,0,0); stB(0,0,1);
    stA(1,1,0);

    if (t < BM) {
        int i = ibase + t; int im = (i < SEQ) ? i : i - SEQ;
        mrow_s[t] = mask[b * SEQ + im] ? 1.0f : 0.0f;
    } else {
        int j = jbase + (t - BM); int jm = (j < SEQ) ? j : j - SEQ;
        mcol_s[t - BM] = mask[b * SEQ + jm] ? 1.0f : 0.0f;
    }
    __syncthreads();   // full drain once: prologue DMAs + mask LDS writes

    // swizzled byte offsets of the two 16B chunks holding k = quad*32..+31
    int as0 = ((2 * quad)     ^ (colq & 7)) * 16;
    int as1 = ((2 * quad + 1) ^ (colq & 7)) * 16;

    auto rdA = [&](int d, int mi) -> i32x8 {
        // wave's A rows: wrow*128 + mi*16 + colq  ->  half = wrow
        const unsigned char* row = &As[d][wrow][mi * 16 + colq][0];
        i32x4 lo = *(const i32x4*)(row + as0);
        i32x4 hi = *(const i32x4*)(row + as1);
        return __builtin_shufflevector(lo, hi, 0, 1, 2, 3, 4, 5, 6, 7);
    };
    auto rdB = [&](int d, int nj) -> i32x8 {
        int J = wcol * 64 + nj * 16 + colq;           // J&7 == colq&7
        const unsigned char* row = &Bs[d][J >> 7][J & 127][0];
        i32x4 lo = *(const i32x4*)(row + as0);
        i32x4 hi = *(const i32x4*)(row + as1);
        return __builtin_shufflevector(lo, hi, 0, 1, 2, 3, 4, 5, 6, 7);
    };

    f32x4 acc[8][4] = {};
    i32x8 a0, a1, a2, a3, p0v, p1v, q0v, q1v;   // named: no address escape

#define SCL 0x7F7F7F7F
#define MM(A,B,M,N) acc[M][N] = __builtin_amdgcn_mfma_scale_f32_16x16x128_f8f6f4( \
        A, B, acc[M][N], 0, 0, 0, SCL, 0, SCL)
#define MQUAD(B0,B1,MG,NG) do { __builtin_amdgcn_s_setprio(1); \
    MM(a0,B0,(MG)*4+0,(NG)*2+0); MM(a0,B1,(MG)*4+0,(NG)*2+1); \
    MM(a1,B0,(MG)*4+1,(NG)*2+0); MM(a1,B1,(MG)*4+1,(NG)*2+1); \
    MM(a2,B0,(MG)*4+2,(NG)*2+0); MM(a2,B1,(MG)*4+2,(NG)*2+1); \
    MM(a3,B0,(MG)*4+3,(NG)*2+0); MM(a3,B1,(MG)*4+3,(NG)*2+1); \
    __builtin_amdgcn_s_setprio(0); } while(0)
#define BARR  __builtin_amdgcn_s_barrier()
#define LGKM0 asm volatile("s_waitcnt lgkmcnt(0)" ::: "memory")
#define VM2   asm volatile("s_waitcnt vmcnt(2)" ::: "memory")
#define VM0   asm volatile("s_waitcnt vmcnt(0)" ::: "memory")

    #pragma unroll 1
    for (int i = 0; i < GITERS - 1; i++) {      // i = 0,1,2
        int k1 = 2*i + 1;
        // ---- phase 1: Q00 of k0 (dbuf0); stage A(k1) h1
        a0 = rdA(0,0); a1 = rdA(0,1); a2 = rdA(0,2); a3 = rdA(0,3);
        p0v = rdB(0,0); p1v = rdB(0,1);
        stA(k1, 1, 1);
        BARR; LGKM0; MQUAD(p0v, p1v, 0, 0); BARR;
        // ---- phase 2: Q01 of k0; stage B(k1) h0
        q0v = rdB(0,2); q1v = rdB(0,3);
        stB(k1, 1, 0);
        BARR; LGKM0; MQUAD(q0v, q1v, 0, 1); BARR;
        // ---- phase 3: Q11 of k0; stage B(k1) h1
        a0 = rdA(0,4); a1 = rdA(0,5); a2 = rdA(0,6); a3 = rdA(0,7);
        stB(k1, 1, 1);
        BARR; LGKM0; MQUAD(q0v, q1v, 1, 1); BARR;
        // ---- phase 4: Q10 of k0; RE-READ p from dbuf0; stage A(k0+2) h0
        p0v = rdB(0,0); p1v = rdB(0,1);
        stA(k1 + 1, 0, 0); VM2;
        BARR; LGKM0; MQUAD(p0v, p1v, 1, 0); BARR;
        // ---- phase 5: Q00 of k1 (dbuf1); stage A(k0+2) h1
        a0 = rdA(1,0); a1 = rdA(1,1); a2 = rdA(1,2); a3 = rdA(1,3);
        p0v = rdB(1,0); p1v = rdB(1,1);
        stA(k1 + 1, 0, 1);
        BARR; LGKM0; MQUAD(p0v, p1v, 0, 0); BARR;
        // ---- phase 6: Q01 of k1; stage B(k0+2) h0
        q0v = rdB(1,2); q1v = rdB(1,3);
        stB(k1 + 1, 0, 0);
        BARR; LGKM0; MQUAD(q0v, q1v, 0, 1); BARR;
        // ---- phase 7: Q11 of k1; stage B(k0+2) h1
        a0 = rdA(1,4); a1 = rdA(1,5); a2 = rdA(1,6); a3 = rdA(1,7);
        stB(k1 + 1, 0, 1);
        BARR; LGKM0; MQUAD(q0v, q1v, 1, 1); BARR;
        // ---- phase 8: Q10 of k1; RE-READ p from dbuf1; stage A(k0+3) h0
        p0v = rdB(1,0); p1v = rdB(1,1);
        stA(k1 + 2, 1, 0); VM2;
        BARR; LGKM0; MQUAD(p0v, p1v, 1, 0); BARR;
    }

    // ---- peeled final iter: k0=6 (dbuf0), k1=7 (dbuf1)
    a0 = rdA(0,0); a1 = rdA(0,1); a2 = rdA(0,2); a3 = rdA(0,3);
    p0v = rdB(0,0); p1v = rdB(0,1);
    stA(7, 1, 1);
    BARR; LGKM0; MQUAD(p0v, p1v, 0, 0); BARR;

    q0v = rdB(0,2); q1v = rdB(0,3);
    stB(7, 1, 0);
    BARR; LGKM0; MQUAD(q0v, q1v, 0, 1); BARR;

    a0 = rdA(0,4); a1 = rdA(0,5); a2 = rdA(0,6); a3 = rdA(0,7);
    stB(7, 1, 1);
    BARR; LGKM0; MQUAD(q0v, q1v, 1, 1); BARR;

    p0v = rdB(0,0); p1v = rdB(0,1);
    VM0;                       // tile 7 fully landed (6 outstanding -> 0)
    BARR; LGKM0;               // every wave past its drain before dbuf1 reads
    MQUAD(p0v, p1v, 1, 0);

    // tail on dbuf1: fully resident, no more staging -> barrier-free
    // (compiler inserts the lgkmcnt waits for these register deps)
    a0 = rdA(1,0); a1 = rdA(1,1); a2 = rdA(1,2); a3 = rdA(1,3);
    p0v = rdB(1,0); p1v = rdB(1,1);
    MQUAD(p0v, p1v, 0, 0);
    q0v = rdB(1,2); q1v = rdB(1,3);
    MQUAD(q0v, q1v, 0, 1);
    a0 = rdA(1,4); a1 = rdA(1,5); a2 = rdA(1,6); a3 = rdA(1,7);
    MQUAD(q0v, q1v, 1, 1);
    p0v = rdB(1,0); p1v = rdB(1,1);
    MQUAD(p0v, p1v, 1, 0);

    // Epilogue.  C/D layout: col = colq, row = quad*4 + reg.
    float mj[4]; int jglob[4];
    #pragma unroll
    for (int nj = 0; nj < 4; nj++) {
        int jl = wcol * 64 + nj * 16 + colq;
        mj[nj] = mcol_s[jl];
        jglob[nj] = jbase + jl;
    }
    float colsum[4] = {0.f, 0.f, 0.f, 0.f};

    #pragma unroll
    for (int mi = 0; mi < 8; mi++) {
        int il0 = wrow * 128 + mi * 16 + quad * 4;
        float rsum[4] = {0.f, 0.f, 0.f, 0.f};
        float mr[4];
        #pragma unroll
        for (int r = 0; r < 4; r++) mr[r] = mrow_s[il0 + r];
        #pragma unroll
        for (int nj = 0; nj < 4; nj++) {
            #pragma unroll
            for (int r = 0; r < 4; r++) {
                int d = (ibase + il0 + r) - jglob[nj];
                bool same = (d == 0) | (d == SEQ) | (d == -SEQ);
                float e = same ? 0.0f : __expf(acc[mi][nj][r] * EXP_SCALE);
                rsum[r] += e * mj[nj];
                colsum[nj] += e * mr[r];
            }
        }
        // reduce each row sum across the 16 column lanes
        #pragma unroll
        for (int r = 0; r < 4; r++) {
            float v = rsum[r];
            #pragma unroll
            for (int m = 1; m < 16; m <<= 1) v += __shfl_xor(v, m, 64);
            if (colq == 0)
                atomicAdd(&Ng[b * SEQ2 + ibase + il0 + r], v);
        }
    }

    if (!isdiag) {
        // reduce col sums across the 4 quads
        #pragma unroll
        for (int nj = 0; nj < 4; nj++) {
            float v = colsum[nj];
            v += __shfl_xor(v, 16, 64);
            v += __shfl_xor(v, 32, 64);
            if (quad == 0)
                atomicAdd(&Ng[b * SEQ2 + jglob[nj]], v);
        }
    }
}

// ---------------------------------------------------------------------------
// Kernel 3: per-batch masked mean of per-token loss, accumulated straight
// into out[0].  per_tok[i] = log1p(Ng[i] * exp(-pos_sim/T)).
// ---------------------------------------------------------------------------
__global__ __launch_bounds__(1024) void loss_kernel(
        const float* __restrict__ Ng, const float* __restrict__ pos_cos,
        const int* __restrict__ mask, float* __restrict__ out) {
    int b = blockIdx.x, t = threadIdx.x;
    float sum = 0.f, cnt = 0.f;
    for (int i = t; i < SEQ2; i += 1024) {
        int im = (i < SEQ) ? i : i - SEQ;
        if (mask[b * SEQ + im]) {
            float ps = pos_cos[b * SEQ + im] * TEMP_INV;
            float ng = Ng[b * SEQ2 + i];
            sum += log1pf(ng * __expf(-ps));
            cnt += 1.0f;
        }
    }
    sum = wave_red64(sum); cnt = wave_red64(cnt);
    __shared__ float rs[16], rc[16];
    int lane = t & 63, w = t >> 6;
    if (lane == 0) { rs[w] = sum; rc[w] = cnt; }
    __syncthreads();
    if (t == 0) {
        float s = 0.f, c = 0.f;
        #pragma unroll
        for (int k = 0; k < 16; k++) { s += rs[k]; c += rc[k]; }
        atomicAdd(out, s / c * (1.0f / BATCH));
    }
}

// ---------------------------------------------------------------------------
extern "C" void kernel_launch(void* const* d_in, const int* in_sizes, int n_in,
                              void* d_out, int out_size, void* d_ws, size_t ws_size,
                              hipStream_t stream) {
    const float* h1  = (const float*)d_in[0];
    const float* h2  = (const float*)d_in[1];
    const int* mask  = (const int*)d_in[2];
    float* out       = (float*)d_out;

    char* ws = (char*)d_ws;
    size_t feats_bytes = (size_t)BATCH * SEQ2 * DIM;          // 25,165,824 (fp8)
    unsigned char* feats = (unsigned char*)ws;
    float* pos_cos    = (float*)(ws + feats_bytes);
    float* Ng         = (float*)(ws + feats_bytes + (size_t)BATCH * SEQ * 4);

    normalize_kernel<<<BATCH * SEQ / 4, 256, 0, stream>>>(h1, h2, feats, pos_cos, Ng, out);

    gemm_ng_kernel<<<NPAIRS * BATCH, 512, 0, stream>>>(feats, mask, Ng);

    loss_kernel<<<BATCH, 1024, 0, stream>>>(Ng, pos_cos, mask, out);
}

// Round 4
// 193.596 us; speedup vs baseline: 1.2018x; 1.2018x over previous
//
#include <hip/hip_runtime.h>
#include <hip/hip_bf16.h>
#include <math.h>

// Problem constants (from reference setup_inputs)
#define BATCH 8
#define SEQ   1536
#define DIM   1024
#define SEQ2  (2*SEQ)          // 3072
#define TEMP_INV 20.0f         // 1 / 0.05
// feats stored as fp8 e4m3 pre-scaled by 8 => sim accumulator carries 64x
#define EXP_SCALE (TEMP_INV / 64.0f)   // 0.3125

// GEMM tiling (R0 known-good geometry, single-buffered for occupancy)
#define BM 128
#define BN 128
#define BK 128                          // fp8 elements per K-tile (128 B/row)
#define KITERS (DIM/BK)                 // 8
#define TILES  (SEQ2 / BM)              // 24
#define NPAIRS (TILES * (TILES+1) / 2)  // 300 upper-triangular tile pairs

typedef int   i32x4 __attribute__((ext_vector_type(4)));
typedef int   i32x8 __attribute__((ext_vector_type(8)));
typedef float f32x4 __attribute__((ext_vector_type(4)));

#define GLOBAL_AS __attribute__((address_space(1)))
#define LDS_AS    __attribute__((address_space(3)))

__device__ inline void async_ld16(const void* g, void* lds_uniform) {
    // gfx950: direct global->LDS, 16B/lane; LDS dest = wave-uniform base + lane*16
    __builtin_amdgcn_global_load_lds((const GLOBAL_AS void*)g, (LDS_AS void*)lds_uniform, 16, 0, 0);
}

__device__ inline float wave_red64(float v) {
    #pragma unroll
    for (int m = 32; m > 0; m >>= 1) v += __shfl_xor(v, m, 64);
    return v;
}

// ---------------------------------------------------------------------------
// Kernel 1: L2-normalize both views -> fp8 e4m3 feats (x8 pre-scale)
// [B][2S][D]; fp32 pos cosine (exact, pre-quantization); zero-init Ng and
// d_out (loss blocks atomicAdd into d_out later in the same stream).
// One WAVE per token: no barriers.
// ---------------------------------------------------------------------------
__global__ __launch_bounds__(256) void normalize_kernel(
        const float* __restrict__ h1, const float* __restrict__ h2,
        unsigned char* __restrict__ feats, float* __restrict__ pos_cos,
        float* __restrict__ Ng, float* __restrict__ out) {
    int w = threadIdx.x >> 6, lane = threadIdx.x & 63;
    int tok = blockIdx.x * 4 + w;                 // 0 .. B*S-1
    int b = tok / SEQ, s = tok - b * SEQ;

    const float4* a4 = (const float4*)(h1 + (size_t)tok * DIM);
    const float4* b4 = (const float4*)(h2 + (size_t)tok * DIM);
    float4 av[4], bv[4];
    #pragma unroll
    for (int it = 0; it < 4; it++) { av[it] = a4[lane + 64*it]; bv[it] = b4[lane + 64*it]; }

    float ss1 = 0.f, ss2 = 0.f, sd = 0.f;
    #pragma unroll
    for (int it = 0; it < 4; it++) {
        ss1 += av[it].x*av[it].x + av[it].y*av[it].y + av[it].z*av[it].z + av[it].w*av[it].w;
        ss2 += bv[it].x*bv[it].x + bv[it].y*bv[it].y + bv[it].z*bv[it].z + bv[it].w*bv[it].w;
        sd  += av[it].x*bv[it].x + av[it].y*bv[it].y + av[it].z*bv[it].z + av[it].w*bv[it].w;
    }
    ss1 = wave_red64(ss1); ss2 = wave_red64(ss2); sd = wave_red64(sd);

    float sc1 = 1.0f / fmaxf(sqrtf(ss1), 1e-12f);
    float sc2 = 1.0f / fmaxf(sqrtf(ss2), 1e-12f);
    float s18 = sc1 * 8.0f, s28 = sc2 * 8.0f;   // x8: keep fp8 values normal

    unsigned int* f1row = (unsigned int*)(feats + ((size_t)b * SEQ2 + s) * DIM);
    unsigned int* f2row = (unsigned int*)(feats + ((size_t)b * SEQ2 + SEQ + s) * DIM);
    #pragma unroll
    for (int it = 0; it < 4; it++) {
        int p1 = __builtin_amdgcn_cvt_pk_fp8_f32(av[it].x * s18, av[it].y * s18, 0, 0);
        p1     = __builtin_amdgcn_cvt_pk_fp8_f32(av[it].z * s18, av[it].w * s18, p1, 1);
        int p2 = __builtin_amdgcn_cvt_pk_fp8_f32(bv[it].x * s28, bv[it].y * s28, 0, 0);
        p2     = __builtin_amdgcn_cvt_pk_fp8_f32(bv[it].z * s28, bv[it].w * s28, p2, 1);
        f1row[lane + 64*it] = (unsigned int)p1;
        f2row[lane + 64*it] = (unsigned int)p2;
    }
    if (lane == 0) {
        pos_cos[tok] = sd * sc1 * sc2;
        Ng[2*tok] = 0.0f;
        Ng[2*tok + 1] = 0.0f;
        if (tok == 0) out[0] = 0.0f;   // loss blocks accumulate into out
    }
}

// ---------------------------------------------------------------------------
// Kernel 2: symmetric fused sim-GEMM + exp + neg-mask, MX-fp8 K=128.
// R0 structure (verified, 84.8 us) with ONE change: SINGLE-buffered LDS
// (33 KB vs 66.5 KB) so 3 blocks fit per CU instead of 2.  The 2-phase
// convoy's barrier-drain stalls are hidden by CROSS-BLOCK wave overlap
// (m114: independent blocks' MFMA and DMA co-schedule); +50% resident
// blocks is the lever.  __launch_bounds__(256,3) declares the target
// (total regs ~160/wave -> 3 waves/SIMD fits).
// Per K-iter schedule (prefetch overlap preserved):
//   frag ds_reads -> __syncthreads (lgkm drain: all waves done reading)
//   -> stage(it+1) into SAME buffer (DMA flies) -> sched_barrier(0)
//   -> 16 MFMA (overlap DMA) -> __syncthreads (vmcnt(0) drain: tile landed)
// LDS swizzle (zero-conflict, R0): chunk c of row r at slot c ^ (r&7).
// ---------------------------------------------------------------------------
__global__ __launch_bounds__(256, 3) void gemm_ng_kernel(
        const unsigned char* __restrict__ feats, const int* __restrict__ mask,
        float* __restrict__ Ng) {
    int bid = blockIdx.x;
    int b = bid & 7;                 // XCD-local batch (m09: placement %8); 2400%8==0
    int p = bid >> 3;                // 0..299 triangular pair index
    int ti = 0;
    while (p >= TILES - ti) { p -= TILES - ti; ti++; }
    int tj = ti + p;
    int ibase = ti * BM, jbase = tj * BN;
    bool isdiag = (ti == tj);

    const unsigned char* fb = feats + (size_t)b * SEQ2 * DIM;

    __shared__ __align__(16) unsigned char As[BM][BK];  // 16 KB single buffer
    __shared__ __align__(16) unsigned char Bs[BN][BK];  // 16 KB
    __shared__ float mrow_s[BM];
    __shared__ float mcol_s[BN];

    int t = threadIdx.x;
    int lane = t & 63, w = t >> 6;
    int wrow = w >> 1, wcol = w & 1;       // 2x2 waves -> 64x64 each
    int colq = lane & 15, quad = lane >> 4;

    // Staging: per issue (4 KB = 32 rows x 128 B), thread t covers row
    // sr = t>>3, stored slot t&7 -> logical source chunk (t&7) ^ (sr&7).
    int sr = t >> 3;
    int sc = (t & 7) ^ (sr & 7);
    const unsigned char* a0 = fb + (size_t)(ibase + sr) * DIM + sc * 16;
    const unsigned char* b0 = fb + (size_t)(jbase + sr) * DIM + sc * 16;

    auto stage = [&](int it) {
        size_t kb = (size_t)it * BK;
        #pragma unroll
        for (int q = 0; q < 4; q++) {       // 32 rows per issue
            async_ld16(a0 + (size_t)q * 32 * DIM + kb, (char*)&As[0][0] + q * 4096 + w * 1024);
            async_ld16(b0 + (size_t)q * 32 * DIM + kb, (char*)&Bs[0][0] + q * 4096 + w * 1024);
        }
    };

    stage(0);                            // first DMA flies during mask setup

    // stage masks (as float) for the tile's rows/cols
    if (t < BM) {
        int i = ibase + t; int im = (i < SEQ) ? i : i - SEQ;
        mrow_s[t] = mask[b * SEQ + im] ? 1.0f : 0.0f;
    } else {
        int j = jbase + (t - BM); int jm = (j < SEQ) ? j : j - SEQ;
        mcol_s[t - BM] = mask[b * SEQ + jm] ? 1.0f : 0.0f;
    }
    __syncthreads();     // compiler-inserted vmcnt(0): tile 0 + masks resident

    f32x4 acc[4][4] = {};
    // swizzled byte offsets of the two 16B chunks holding k = quad*32..+31
    int s0 = ((2 * quad)     ^ (colq & 7)) * 16;
    int s1 = ((2 * quad + 1) ^ (colq & 7)) * 16;

    #pragma unroll 1
    for (int it = 0; it < KITERS; it++) {
        i32x8 af[4], bg[4];
        #pragma unroll
        for (int mi = 0; mi < 4; mi++) {
            int row = wrow * 64 + mi * 16 + colq;   // row&7 == colq&7
            i32x4 lo = *(const i32x4*)&As[row][s0];
            i32x4 hi = *(const i32x4*)&As[row][s1];
            af[mi] = __builtin_shufflevector(lo, hi, 0, 1, 2, 3, 4, 5, 6, 7);
        }
        #pragma unroll
        for (int nj = 0; nj < 4; nj++) {
            int row = wcol * 64 + nj * 16 + colq;
            i32x4 lo = *(const i32x4*)&Bs[row][s0];
            i32x4 hi = *(const i32x4*)&Bs[row][s1];
            bg[nj] = __builtin_shufflevector(lo, hi, 0, 1, 2, 3, 4, 5, 6, 7);
        }

        // All waves' frag reads complete (each wave's lgkmcnt(0) is emitted
        // by the compiler before s_barrier) -> buffer safe to overwrite.
        __syncthreads();

        if (it + 1 < KITERS) {
            stage(it + 1);                          // DMA next tile, same buffer
            __builtin_amdgcn_sched_barrier(0);      // keep MFMAs BELOW the issue
        }

        #pragma unroll
        for (int mi = 0; mi < 4; mi++)
            #pragma unroll
            for (int nj = 0; nj < 4; nj++)
                acc[mi][nj] = __builtin_amdgcn_mfma_scale_f32_16x16x128_f8f6f4(
                    af[mi], bg[nj], acc[mi][nj],
                    0, 0,                       // cbsz=fp8, blgp=fp8
                    0, 0x7F7F7F7F,              // opselA, scaleA = 2^0
                    0, 0x7F7F7F7F);             // opselB, scaleB = 2^0

        if (it + 1 < KITERS)
            __syncthreads();   // compiler-inserted vmcnt(0): next tile landed
    }

    // Epilogue.  C/D layout: col = colq, row = quad*4 + reg.
    float mj[4]; int jglob[4];
    #pragma unroll
    for (int nj = 0; nj < 4; nj++) {
        int jl = wcol * 64 + nj * 16 + colq;
        mj[nj] = mcol_s[jl];
        jglob[nj] = jbase + jl;
    }
    float colsum[4] = {0.f, 0.f, 0.f, 0.f};

    #pragma unroll
    for (int mi = 0; mi < 4; mi++) {
        int il0 = wrow * 64 + mi * 16 + quad * 4;
        float rsum[4] = {0.f, 0.f, 0.f, 0.f};
        float mr[4];
        #pragma unroll
        for (int r = 0; r < 4; r++) mr[r] = mrow_s[il0 + r];
        #pragma unroll
        for (int nj = 0; nj < 4; nj++) {
            #pragma unroll
            for (int r = 0; r < 4; r++) {
                int d = (ibase + il0 + r) - jglob[nj];
                bool same = (d == 0) | (d == SEQ) | (d == -SEQ);
                float e = same ? 0.0f : __expf(acc[mi][nj][r] * EXP_SCALE);
                rsum[r] += e * mj[nj];
                colsum[nj] += e * mr[r];
            }
        }
        // reduce each row sum across the 16 column lanes
        #pragma unroll
        for (int r = 0; r < 4; r++) {
            float v = rsum[r];
            #pragma unroll
            for (int m = 1; m < 16; m <<= 1) v += __shfl_xor(v, m, 64);
            if (colq == 0)
                atomicAdd(&Ng[b * SEQ2 + ibase + il0 + r], v);
        }
    }

    if (!isdiag) {
        // reduce col sums across the 4 quads
        #pragma unroll
        for (int nj = 0; nj < 4; nj++) {
            float v = colsum[nj];
            v += __shfl_xor(v, 16, 64);
            v += __shfl_xor(v, 32, 64);
            if (quad == 0)
                atomicAdd(&Ng[b * SEQ2 + jglob[nj]], v);
        }
    }
}

// ---------------------------------------------------------------------------
// Kernel 3: per-batch masked mean of per-token loss, accumulated straight
// into out[0].  per_tok[i] = log1p(Ng[i] * exp(-pos_sim/T)).
// ---------------------------------------------------------------------------
__global__ __launch_bounds__(1024) void loss_kernel(
        const float* __restrict__ Ng, const float* __restrict__ pos_cos,
        const int* __restrict__ mask, float* __restrict__ out) {
    int b = blockIdx.x, t = threadIdx.x;
    float sum = 0.f, cnt = 0.f;
    for (int i = t; i < SEQ2; i += 1024) {
        int im = (i < SEQ) ? i : i - SEQ;
        if (mask[b * SEQ + im]) {
            float ps = pos_cos[b * SEQ + im] * TEMP_INV;
            float ng = Ng[b * SEQ2 + i];
            sum += log1pf(ng * __expf(-ps));
            cnt += 1.0f;
        }
    }
    sum = wave_red64(sum); cnt = wave_red64(cnt);
    __shared__ float rs[16], rc[16];
    int lane = t & 63, w = t >> 6;
    if (lane == 0) { rs[w] = sum; rc[w] = cnt; }
    __syncthreads();
    if (t == 0) {
        float s = 0.f, c = 0.f;
        #pragma unroll
        for (int k = 0; k < 16; k++) { s += rs[k]; c += rc[k]; }
        atomicAdd(out, s / c * (1.0f / BATCH));
    }
}

// ---------------------------------------------------------------------------
extern "C" void kernel_launch(void* const* d_in, const int* in_sizes, int n_in,
                              void* d_out, int out_size, void* d_ws, size_t ws_size,
                              hipStream_t stream) {
    const float* h1  = (const float*)d_in[0];
    const float* h2  = (const float*)d_in[1];
    const int* mask  = (const int*)d_in[2];
    float* out       = (float*)d_out;

    char* ws = (char*)d_ws;
    size_t feats_bytes = (size_t)BATCH * SEQ2 * DIM;          // 25,165,824 (fp8)
    unsigned char* feats = (unsigned char*)ws;
    float* pos_cos    = (float*)(ws + feats_bytes);
    float* Ng         = (float*)(ws + feats_bytes + (size_t)BATCH * SEQ * 4);

    normalize_kernel<<<BATCH * SEQ / 4, 256, 0, stream>>>(h1, h2, feats, pos_cos, Ng, out);

    gemm_ng_kernel<<<NPAIRS * BATCH, 256, 0, stream>>>(feats, mask, Ng);

    loss_kernel<<<BATCH, 1024, 0, stream>>>(Ng, pos_cos, mask, out);
}